// Round 1
// 129.557 us; speedup vs baseline: 1.0092x; 1.0092x over previous
//
#include <hip/hip_runtime.h>

// Problem dims (fixed by setup_inputs): B=16, A=9, H=56, W=56, N=64.
// Output: (B, A*H*W, N) fp32 IoU matrix (110.25 MiB). Write-roofline ~19 us.
//
// R7: replace the shfl-transpose (64 ds_bpermute/thread) with a wave-private
//   LDS slab: 1 ds_write_b128 (own decoded box) + 16 broadcast ds_read_b128
//   (proposal 4j+q; 16 lanes/address, 4 distinct 16B-apart addresses per
//   instr -> conflict-free). Wave-synchronous: no __syncthreads anywhere.
//   Motivation: the old 16x-unrolled shfl loop lets the scheduler hoist all
//   64 cross-lane results (register blowup / possible scratch spill) and puts
//   64 bpermutes/thread on the LDS pipe. This form needs ~17 LDS ops/thread
//   and addresses the 16 reads with one base reg + immediate offsets.
//   Store structure unchanged: lane L -> row q=L>>4, bbox group g=L&15;
//   each iter j stores one dwordx4 -> dense contiguous 1KB per wave-instr,
//   16KB linear per wave (the verified fill-alike pattern).

constexpr int B_ = 16;
constexpr int A_ = 9;
constexpr int H_ = 56;
constexpr int W_ = 56;
constexpr int N_ = 64;
constexpr int HW_ = H_ * W_;            // 3136
constexpr int P_ = A_ * HW_;            // 28224 proposals per batch
constexpr int WPB = P_ / 64;            // 441 waves per batch
constexpr int NWAVES = B_ * WPB;        // 7056
constexpr int BLOCK = 256;
constexpr int WVB = BLOCK / 64;         // 4 waves per block

typedef float floatx4 __attribute__((ext_vector_type(4)));

__global__ __launch_bounds__(BLOCK) void ssd_iou_kernel(
    const float* __restrict__ anc,      // (A,2)
    const float* __restrict__ grid,     // (B,H,W,2)
    const float* __restrict__ offsets,  // (B,A,H,W,4)
    const float* __restrict__ bboxes,   // (B,N,5)
    float* __restrict__ out)            // (B, P, N)
{
    // wave-private slabs: 64 proposals x 16B = 1KB per wave, 4KB per block.
    __shared__ float4 prop[WVB][64];

    const int t    = blockIdx.x * BLOCK + threadIdx.x;
    const int w    = t >> 6;            // global wave id, 0..7055
    const int lane = t & 63;
    const int wib  = threadIdx.x >> 6;  // wave-in-block

    const int b  = w / WPB;             // batch (wave-uniform)
    const int lp = (w - b * WPB) * 64 + lane;   // this lane's local proposal

    // ---- decode own proposal ----
    const int a  = lp / HW_;
    const int hw = lp - a * HW_;

    const float4 off = reinterpret_cast<const float4*>(offsets)[b * P_ + lp];
    const float2 g   = reinterpret_cast<const float2*>(grid)[b * HW_ + hw];
    const float2 an  = reinterpret_cast<const float2*>(anc)[a];

    const float xc = g.x + off.x;
    const float yc = g.y + off.y;
    const float wp = an.x * __expf(off.z);
    const float hp = an.y * __expf(off.w);

    float4 mybox;
    mybox.x = xc - 0.5f * wp;
    mybox.y = yc - 0.5f * hp;
    mybox.z = xc + 0.5f * wp;
    mybox.w = yc + 0.5f * hp;

    // publish own box to the wave slab (ds_write_b128; same-wave RAW is
    // ordered via lgkmcnt -- no barrier needed, slab is wave-private).
    prop[wib][lane] = mybox;

    // ---- per-lane bbox constants (4 boxes; 20KB table -> L1-resident) ----
    const int q   = lane >> 4;          // row sub-index within group of 4
    const int g16 = lane & 15;          // bbox group: bboxes 4g..4g+3

    float bx0[4], by0[4], bx1[4], by1[4], aob[4];
    #pragma unroll
    for (int k = 0; k < 4; ++k) {
        const float* bb = bboxes + ((size_t)(b * N_ + 4 * g16 + k)) * 5;
        bx0[k] = bb[0];
        by0[k] = bb[1];
        bx1[k] = bb[2];
        by1[k] = bb[3];
        aob[k] = (bx1[k] - bx0[k]) * (by1[k] - by0[k]);
    }

    // out rows for this wave start at proposal w*64; wave writes 16KB linear.
    float* obase = out + (size_t)w * (64 * N_) + q * N_ + 4 * g16;

    #pragma unroll
    for (int j = 0; j < 16; ++j) {
        // broadcast read of proposal 4j+q: lanes 0-15 -> one address,
        // 16-31 -> +16B, 32-47 -> +32B, 48-63 -> +48B  => conflict-free.
        const float4 p = prop[wib][4 * j + q];
        const float aop = (p.z - p.x) * (p.w - p.y);

        floatx4 res;
        #pragma unroll
        for (int k = 0; k < 4; ++k) {
            const float tlx = fmaxf(p.x, bx0[k]);
            const float tly = fmaxf(p.y, by0[k]);
            const float brx = fminf(p.z, bx1[k]);
            const float bry = fminf(p.w, by1[k]);

            const float iw  = fmaxf(brx - tlx, 0.0f);
            const float ih  = fmaxf(bry - tly, 0.0f);
            const float aoi = iw * ih;

            const float denom = aop + aob[k] - aoi;
            res[k] = aoi * __builtin_amdgcn_rcpf(denom);
        }

        *reinterpret_cast<floatx4*>(obase + (size_t)j * (4 * N_)) = res;
    }
}

extern "C" void kernel_launch(void* const* d_in, const int* in_sizes, int n_in,
                              void* d_out, int out_size, void* d_ws, size_t ws_size,
                              hipStream_t stream) {
    const float* anc     = (const float*)d_in[0];
    const float* grid    = (const float*)d_in[1];
    const float* offsets = (const float*)d_in[2];
    const float* bboxes  = (const float*)d_in[3];
    float* out = (float*)d_out;

    const int nblocks = (NWAVES * 64) / BLOCK;   // 1764
    ssd_iou_kernel<<<nblocks, BLOCK, 0, stream>>>(anc, grid, offsets, bboxes, out);
}